// Round 5
// baseline (93.872 us; speedup 1.0000x reference)
//
#include <hip/hip_runtime.h>

#define M_DIM 64
#define K_DIM 8192
#define N_DIM 8192
#define QB 32
#define NT 64                      // cols per block (16 per wave)
#define KC 64                      // k per stage (2 quant blocks)
#define SPLITS 8
#define KSPLIT (K_DIM / SPLITS)    // 1024
#define NSTAGE (KSPLIT / KC)       // 16

typedef __attribute__((ext_vector_type(8))) short short8;     // MFMA A/B frag
typedef __attribute__((ext_vector_type(8))) unsigned short ushort8;
typedef __attribute__((ext_vector_type(4))) float f32x4;

static_assert(NSTAGE * KC == KSPLIT, "tiling");

// f32 -> bf16 round-to-nearest-even
__device__ __forceinline__ unsigned short f2bf(float f) {
    unsigned u = __builtin_bit_cast(unsigned, f);
    u += 0x7fffu + ((u >> 16) & 1u);
    return (unsigned short)(u >> 16);
}

// Fallback-path only: rewrites whole output with bias every call.
__global__ __launch_bounds__(256) void bias_init(const float* __restrict__ bias,
                                                 float* __restrict__ out) {
    int i = (blockIdx.x * 256 + threadIdx.x) * 4;
    *(f32x4*)(out + i) = *(const f32x4*)(bias + (i & (N_DIM - 1)));
}

// One-shot x f32 -> bf16 into workspace (1 MB, L2-resident).
__global__ __launch_bounds__(256) void xcvt(const float* __restrict__ x,
                                            unsigned short* __restrict__ xb) {
    int i = (blockIdx.x * 256 + threadIdx.x) * 8;
    f32x4 a = *(const f32x4*)(x + i);
    f32x4 b = *(const f32x4*)(x + i + 4);
    ushort8 o;
    #pragma unroll
    for (int e = 0; e < 4; ++e) { o[e] = f2bf(a[e]); o[4 + e] = f2bf(b[e]); }
    *(ushort8*)(xb + i) = o;
}

// R1-validated barrier structure. Deltas vs R1: no x LDS tile (A-frags direct
// from L2-resident bf16 xb, loaded BEFORE the barrier so the drain covers
// them), partial-sum stores instead of atomics, 4 blocks/CU.
template <bool XBF, bool PART>
__global__ __launch_bounds__(256, 4) void qgemm(
    const float* __restrict__ x,             // [M][K] f32 (fallback)
    const unsigned short* __restrict__ xb,   // [M][K] bf16 (main)
    const float* __restrict__ scales,        // [K/QB][N]
    const float* __restrict__ zeros,         // [K/QB][N]
    const int*   __restrict__ qw,            // [K][N], 0..255
    float*       __restrict__ outp)          // PART ? partials [SPLITS][M][N] : out [M][N]
{
    // Block-shared transposed weight tile [col 64][k 64], double-buffered.
    // Row stride 72 shorts = 144 B (16B-aligned b128 reads). R1-validated.
    __shared__ unsigned short lq[2][NT][72];

    const int tid  = threadIdx.x;
    const int lane = tid & 63;
    const int w    = tid >> 6;      // wave: owns cols [n0+16w, n0+16w+16)
    const int q    = lane >> 4;     // k-slot / C row-quarter
    const int lm   = lane & 15;

    const int n0 = blockIdx.x * NT;
    const int k0 = blockIdx.y * KSPLIT;
    const int qn = n0 + lane;       // this lane's weight column

    const int*   qp = qw     + (size_t)k0 * N_DIM + qn;
    const float* sp = scales + (size_t)(k0 >> 5) * N_DIM + qn;
    const float* zp = zeros  + (size_t)(k0 >> 5) * N_DIM + qn;

    // Prologue: stage-0 weights + scales. Per wave-instruction: 64
    // consecutive dwords (256 B) -> fully coalesced.
    int qv[16];
    #pragma unroll
    for (int s = 0; s < 4; ++s)
        #pragma unroll
        for (int j = 0; j < 4; ++j)
            qv[4 * s + j] = __builtin_nontemporal_load(
                qp + (size_t)(16 * s + 4 * w + j) * N_DIM);
    float sv0 = sp[0], sv1 = sp[N_DIM];
    float zv0 = zp[0], zv1 = zp[N_DIM];

    f32x4 acc[4];
    #pragma unroll
    for (int r = 0; r < 4; ++r) acc[r] = (f32x4){0.f, 0.f, 0.f, 0.f};

    for (int t = 0; t < NSTAGE; ++t) {
        const int cur = t & 1;

        // (0) A-fragments for stage t (L2-hot). Issued before the barrier so
        // its vmcnt(0) drain covers them — no extra FIFO stall.
        short8 afr[4][2];
        if (XBF) {
            const unsigned short* xp = xb + (size_t)lm * K_DIM + (k0 + t * KC) + 8 * q;
            #pragma unroll
            for (int rf = 0; rf < 4; ++rf)
                #pragma unroll
                for (int c = 0; c < 2; ++c)
                    afr[rf][c] = *(const short8*)(xp + (size_t)rf * 16 * K_DIM + 32 * c);
        } else {
            #pragma unroll
            for (int rf = 0; rf < 4; ++rf)
                #pragma unroll
                for (int c = 0; c < 2; ++c) {
                    const float* xp = x + (size_t)(16 * rf + lm) * K_DIM
                                        + (k0 + t * KC) + 32 * c + 8 * q;
                    f32x4 u = *(const f32x4*)xp;
                    f32x4 v = *(const f32x4*)(xp + 4);
                    #pragma unroll
                    for (int e = 0; e < 4; ++e) {
                        afr[rf][c][e]     = (short)f2bf(u[e]);
                        afr[rf][c][4 + e] = (short)f2bf(v[e]);
                    }
                }
        }

        // (1) dequant stage-t regs -> packed bf16 (frees qv)
        const float nz0 = -sv0 * zv0, nz1 = -sv1 * zv1;
        uint2 qd[4];
        #pragma unroll
        for (int s = 0; s < 4; ++s) {
            const float sc = (s < 2) ? sv0 : sv1;
            const float nz = (s < 2) ? nz0 : nz1;
            unsigned short h0 = f2bf(fmaf((float)qv[4 * s + 0], sc, nz));
            unsigned short h1 = f2bf(fmaf((float)qv[4 * s + 1], sc, nz));
            unsigned short h2 = f2bf(fmaf((float)qv[4 * s + 2], sc, nz));
            unsigned short h3 = f2bf(fmaf((float)qv[4 * s + 3], sc, nz));
            qd[s].x = (unsigned)h0 | ((unsigned)h1 << 16);
            qd[s].y = (unsigned)h2 | ((unsigned)h3 << 16);
        }

        // (2) prefetch weights + scales for stage t+1 (in flight to barrier)
        if (t + 1 < NSTAGE) {
            const int* p = qp + (size_t)(t + 1) * KC * N_DIM;
            #pragma unroll
            for (int s = 0; s < 4; ++s)
                #pragma unroll
                for (int j = 0; j < 4; ++j)
                    qv[4 * s + j] = __builtin_nontemporal_load(
                        p + (size_t)(16 * s + 4 * w + j) * N_DIM);
            sv0 = sp[(size_t)(2 * t + 2) * N_DIM];
            sv1 = sp[(size_t)(2 * t + 3) * N_DIM];
            zv0 = zp[(size_t)(2 * t + 2) * N_DIM];
            zv1 = zp[(size_t)(2 * t + 3) * N_DIM];
        }

        // (3) stage dequanted tile to LDS (transposed [col][k], R1 layout)
        #pragma unroll
        for (int s = 0; s < 4; ++s)
            *(uint2*)&lq[cur][lane][16 * s + 4 * w] = qd[s];

        // (4) one barrier per stage; drains all vmem (R1 cost model, now
        // covered by 4 independent blocks/CU)
        __syncthreads();

        // (5,6) B-frags from LDS + MFMA
        #pragma unroll
        for (int c = 0; c < 2; ++c) {
            const short8 bf = *(const short8*)&lq[cur][16 * w + lm][32 * c + 8 * q];
            #pragma unroll
            for (int rf = 0; rf < 4; ++rf)
                acc[rf] = __builtin_amdgcn_mfma_f32_16x16x32_bf16(afr[rf][c], bf, acc[rf], 0, 0, 0);
        }
    }

    // Epilogue: C layout col=lane&15, row=4*(lane>>4)+e (R1-validated).
    const int cn = n0 + 16 * w + lm;
    if (PART) {
        float* po = outp + (size_t)blockIdx.y * (M_DIM * (size_t)N_DIM);
        #pragma unroll
        for (int rf = 0; rf < 4; ++rf) {
            const int m = 16 * rf + 4 * q;
            #pragma unroll
            for (int e = 0; e < 4; ++e)
                po[(size_t)(m + e) * N_DIM + cn] = acc[rf][e];
        }
    } else {
        #pragma unroll
        for (int rf = 0; rf < 4; ++rf) {
            const int m = 16 * rf + 4 * q;
            #pragma unroll
            for (int e = 0; e < 4; ++e)
                atomicAdd(outp + (size_t)(m + e) * N_DIM + cn, acc[rf][e]);
        }
    }
}

// out = bias + sum over splits of partials. Fully overwrites d_out each call.
__global__ __launch_bounds__(256) void reduce_bias(const float* __restrict__ part,
                                                   const float* __restrict__ bias,
                                                   float* __restrict__ out) {
    int i = (blockIdx.x * 256 + threadIdx.x) * 4;
    f32x4 s = *(const f32x4*)(bias + (i & (N_DIM - 1)));
    #pragma unroll
    for (int sp = 0; sp < SPLITS; ++sp)
        s += *(const f32x4*)(part + (size_t)sp * (M_DIM * (size_t)N_DIM) + i);
    *(f32x4*)(out + i) = s;
}

extern "C" void kernel_launch(void* const* d_in, const int* in_sizes, int n_in,
                              void* d_out, int out_size, void* d_ws, size_t ws_size,
                              hipStream_t stream) {
    const float* x      = (const float*)d_in[0];
    const float* scales = (const float*)d_in[1];
    const float* zeros  = (const float*)d_in[2];
    const float* bias   = (const float*)d_in[3];
    const int*   qw     = (const int*)d_in[4];
    float* out = (float*)d_out;

    unsigned short* xbf = (unsigned short*)d_ws;
    float* part = (float*)((char*)d_ws + (2u << 20));   // after 2MB xb slot
    const size_t need = (2u << 20) + (size_t)SPLITS * M_DIM * N_DIM * sizeof(float);

    if (ws_size >= need) {
        xcvt<<<dim3((M_DIM * K_DIM) / 2048), 256, 0, stream>>>(x, xbf);
        qgemm<true, true><<<dim3(N_DIM / NT, SPLITS), 256, 0, stream>>>(
            x, xbf, scales, zeros, qw, part);
        reduce_bias<<<dim3((M_DIM * N_DIM) / 1024), 256, 0, stream>>>(part, bias, out);
    } else {
        bias_init<<<dim3((M_DIM * N_DIM) / 1024), 256, 0, stream>>>(bias, out);
        qgemm<false, false><<<dim3(N_DIM / NT, SPLITS), 256, 0, stream>>>(
            x, nullptr, scales, zeros, qw, out);
    }
}

// Round 6
// 62.261 us; speedup vs baseline: 1.5077x; 1.5077x over previous
//
#include <hip/hip_runtime.h>

#define M_DIM 64
#define K_DIM 8192
#define N_DIM 8192
#define QB 32
#define NT 64               // N columns per block
#define KC 64               // K per stage (2 quant blocks)
#define SPLITS 8
#define KSPLIT (K_DIM / SPLITS)    // 1024
#define NSTAGE (KSPLIT / KC)       // 16

typedef __attribute__((ext_vector_type(8))) short short8;     // 8 bf16 (4 VGPRs) - MFMA A/B frag
typedef __attribute__((ext_vector_type(8))) unsigned short ushort8;
typedef __attribute__((ext_vector_type(4))) float f32x4;

static_assert(NSTAGE * KC == KSPLIT, "split must tile");

// f32 -> bf16 round-to-nearest-even (no NaN inputs here)
__device__ __forceinline__ unsigned short f2bf(float f) {
    unsigned u = __builtin_bit_cast(unsigned, f);
    u += 0x7fffu + ((u >> 16) & 1u);
    return (unsigned short)(u >> 16);
}

// Rewrites the whole output with bias every call (d_out is poisoned once and
// never re-poisoned between replays; main kernel atomicAdds on top of this).
__global__ __launch_bounds__(256) void bias_init(const float* __restrict__ bias,
                                                 float* __restrict__ out) {
    int i = (blockIdx.x * 256 + threadIdx.x) * 4;
    int n = i & (N_DIM - 1);
    *(f32x4*)(out + i) = *(const f32x4*)(bias + n);
}

// R1 structure verbatim; only deltas: SPLITS 4->8 (grid 1024 = 4 blocks/CU)
// and __launch_bounds__(256,4) to guarantee the <=128-VGPR allocation that
// occupancy needs. Everything else identical to the 60.2us baseline.
__global__ __launch_bounds__(256, 4) void qgemm(
    const float* __restrict__ x,       // [M][K]
    const float* __restrict__ scales,  // [K/QB][N]
    const float* __restrict__ zeros,   // [K/QB][N]
    const int*   __restrict__ qw,      // [K][N], values 0..255
    float*       __restrict__ out)     // [M][N]
{
    // Transposed weight tile [n][k] and x tile [m][k], bf16, double-buffered.
    // Row stride 72 elems = 144 B: multiple of 16 B (b128-aligned reads).
    __shared__ unsigned short lq[2][NT][72];
    __shared__ unsigned short lx[2][M_DIM][72];

    const int tid  = threadIdx.x;
    const int lane = tid & 63;
    const int w    = tid >> 6;          // wave 0..3, owns cols [16w,16w+16)

    const int n0 = blockIdx.x * NT;
    const int k0 = blockIdx.y * KSPLIT;

    const int qn   = n0 + lane;         // this thread's weight column
    const int xrow = tid >> 2;          // x staging: row 0..63
    const int xcol = (tid & 3) * 16;    // 16 k's per thread

    // stage registers
    int   qv[16];                       // 4 sets x 4 adjacent k, one column
    float sv0, sv1, zv0, zv1;
    f32x4 xv[4];

    auto load_stage = [&](int kk) {
        // weights: set s, elem j -> row kk+16s+4w+j, col qn.
        // Per wave per instr: 64 consecutive dwords (256B) -> fully coalesced.
        #pragma unroll
        for (int s = 0; s < 4; ++s)
            #pragma unroll
            for (int j = 0; j < 4; ++j)
                qv[s * 4 + j] = qw[(size_t)(kk + 16 * s + 4 * w + j) * N_DIM + qn];
        const int b0 = kk >> 5;
        sv0 = scales[(size_t)b0 * N_DIM + qn];
        sv1 = scales[(size_t)(b0 + 1) * N_DIM + qn];
        zv0 = zeros[(size_t)b0 * N_DIM + qn];
        zv1 = zeros[(size_t)(b0 + 1) * N_DIM + qn];
        #pragma unroll
        for (int i = 0; i < 4; ++i)
            xv[i] = *(const f32x4*)(x + (size_t)xrow * K_DIM + kk + xcol + 4 * i);
    };

    load_stage(k0);

    f32x4 acc[4];
    #pragma unroll
    for (int r = 0; r < 4; ++r) acc[r] = (f32x4){0.f, 0.f, 0.f, 0.f};

    for (int t = 0; t < NSTAGE; ++t) {
        const int cur = t & 1;

        // --- dequant stage-t regs -> packed bf16 ---
        const float nz0 = -sv0 * zv0, nz1 = -sv1 * zv1;
        const float s0r = sv0, s1r = sv1;
        uint2 qd[4];
        #pragma unroll
        for (int s = 0; s < 4; ++s) {
            const float sc = (s < 2) ? s0r : s1r;
            const float nz = (s < 2) ? nz0 : nz1;
            unsigned short h0 = f2bf(fmaf((float)qv[s * 4 + 0], sc, nz));
            unsigned short h1 = f2bf(fmaf((float)qv[s * 4 + 1], sc, nz));
            unsigned short h2 = f2bf(fmaf((float)qv[s * 4 + 2], sc, nz));
            unsigned short h3 = f2bf(fmaf((float)qv[s * 4 + 3], sc, nz));
            qd[s].x = (unsigned)h0 | ((unsigned)h1 << 16);
            qd[s].y = (unsigned)h2 | ((unsigned)h3 << 16);
        }
        ushort8 xw0, xw1;
        #pragma unroll
        for (int e = 0; e < 4; ++e) {
            xw0[e]     = f2bf(xv[0][e]);
            xw0[4 + e] = f2bf(xv[1][e]);
            xw1[e]     = f2bf(xv[2][e]);
            xw1[4 + e] = f2bf(xv[3][e]);
        }

        // --- issue loads for stage t+1 (in flight across the barrier) ---
        if (t + 1 < NSTAGE) load_stage(k0 + (t + 1) * KC);

        // --- stage to LDS (transposed [n][k] for B, [m][k] for A) ---
        #pragma unroll
        for (int s = 0; s < 4; ++s)
            *(uint2*)&lq[cur][lane][16 * s + 4 * w] = qd[s];
        *(ushort8*)&lx[cur][xrow][xcol]     = xw0;
        *(ushort8*)&lx[cur][xrow][xcol + 8] = xw1;

        __syncthreads();

        // --- MFMA: wave w = cols [16w,16w+16), all 64 rows, K step 32 ---
        #pragma unroll
        for (int c = 0; c < 2; ++c) {
            const short8 bf = *(const short8*)&lq[cur][16 * w + (lane & 15)]
                                                [32 * c + 8 * (lane >> 4)];
            #pragma unroll
            for (int r = 0; r < 4; ++r) {
                const short8 af = *(const short8*)&lx[cur][16 * r + (lane & 15)]
                                                    [32 * c + 8 * (lane >> 4)];
                acc[r] = __builtin_amdgcn_mfma_f32_16x16x32_bf16(af, bf, acc[r], 0, 0, 0);
            }
        }
    }

    // --- epilogue: C layout col=lane&15, row=4*(lane>>4)+e (verified) ---
    const int cn = n0 + 16 * w + (lane & 15);
    #pragma unroll
    for (int r = 0; r < 4; ++r) {
        const int m = 16 * r + 4 * (lane >> 4);
        #pragma unroll
        for (int e = 0; e < 4; ++e)
            atomicAdd(out + (size_t)(m + e) * N_DIM + cn, acc[r][e]);
    }
}

extern "C" void kernel_launch(void* const* d_in, const int* in_sizes, int n_in,
                              void* d_out, int out_size, void* d_ws, size_t ws_size,
                              hipStream_t stream) {
    const float* x      = (const float*)d_in[0];
    const float* scales = (const float*)d_in[1];
    const float* zeros  = (const float*)d_in[2];
    const float* bias   = (const float*)d_in[3];
    const int*   qw     = (const int*)d_in[4];
    float* out = (float*)d_out;

    bias_init<<<dim3((M_DIM * N_DIM) / 1024), 256, 0, stream>>>(bias, out);
    qgemm<<<dim3(N_DIM / NT, SPLITS), 256, 0, stream>>>(x, scales, zeros, qw, out);
}